// Round 4
// baseline (140.405 us; speedup 1.0000x reference)
//
#include <hip/hip_runtime.h>
#include <math.h>

// Problem constants (from reference setup_inputs)
#define NN 256   // nodes
#define FF 256   // feature dim
#define BB 32    // batch
#define EE 8192  // edges (N * DEG)

#define FGROUPS 4      // grid.y; features per block = FF/FGROUPS = 64 (16 float4)
#define CAP 1024       // max supported in-degree (actual ~60; mean 32)
#define EPT (EE / 4 / 256)   // int4 edge-quads per thread = 8

// ---------------------------------------------------------------------------
// Single fused kernel, FULLY DETERMINISTIC (no atomics anywhere):
//   Phase 1a: thread t scans its 32 consecutive edges (8 int4), counts
//             dst==d matches and src==d hits.
//   Scan:     packed Hillis-Steele inclusive scan over the 256 threads
//             (cnt low 16 bits | srccnt high 16) -> exclusive base + totals.
//   Phase 1b: re-scan (L1-hot) and write (s, cos(phase[s,d])) at the scan
//             offset IN EDGE ORDER -> bit-identical LDS list on every run,
//             fixed summation order (required: harness re-validates d_out
//             after graph replays; any run-to-run divergence fails).
//   Phase 2:  pad to multiple of 4 (s=0,c=0 dummies = exact no-ops),
//             unroll-4 gather-accumulate; 4 blocks/CU hide L2/L3 latency.
// Thread layout: f4 = tid&15 (16 float4 f-slices), b0 = (tid>>4)*2
// (16 groups x 2 batches). W load is a 4-lane broadcast within the wave.
// ---------------------------------------------------------------------------
__device__ __forceinline__ void fma4(float4& a, const float4 x, const float4 w) {
    a.x = fmaf(x.x, w.x, a.x);
    a.y = fmaf(x.y, w.y, a.y);
    a.z = fmaf(x.z, w.z, a.z);
    a.w = fmaf(x.w, w.w, a.w);
}

__global__ __launch_bounds__(256) void fused_propagate_kernel(
    const float4* __restrict__ nf4,    // [BB, NN, FF/4]
    const float4* __restrict__ W4,     // [NN, NN, FF/4]
    const float*  __restrict__ phase,  // [NN, NN]
    const int*    __restrict__ src,    // [EE]
    const int*    __restrict__ dst,    // [EE]
    float4*       __restrict__ out4)   // [BB, NN, FF/4]
{
    const int d   = blockIdx.x;
    const int tid = threadIdx.x;
    const int f4  = blockIdx.y * (FF / 4 / FGROUPS) + (tid & 15);
    const int b0  = (tid >> 4) * 2;

    __shared__ int   ls[CAP];
    __shared__ float lc[CAP];
    __shared__ int   sc[256];

    const int4* dst4 = (const int4*)dst;
    const int4* src4 = (const int4*)src;
    const int   i0   = tid * EPT;

    // ---- Phase 1a: count matches in my contiguous edge range ----
    int cnt = 0, msrc = 0;
    for (int i = 0; i < EPT; i++) {
        const int4 dv = dst4[i0 + i];
        const int4 sv = src4[i0 + i];
        cnt  += (dv.x == d) + (dv.y == d) + (dv.z == d) + (dv.w == d);
        msrc += (sv.x == d) + (sv.y == d) + (sv.z == d) + (sv.w == d);
    }

    // ---- packed inclusive scan (deterministic, barrier-only) ----
    sc[tid] = cnt | (msrc << 16);
    __syncthreads();
    for (int off = 1; off < 256; off <<= 1) {
        int v = 0;
        if (tid >= off) v = sc[tid - off];
        __syncthreads();
        if (tid >= off) sc[tid] += v;
        __syncthreads();
    }
    const int totals = sc[255];
    const int n      = totals & 0xFFFF;          // total matched edges (<= CAP)
    const int srccnt = totals >> 16;             // out-degree of node d
    int base = (sc[tid] & 0xFFFF) - cnt;         // my exclusive write offset

    // ---- Phase 1b: write (s, cos) in edge order ----
    for (int i = 0; i < EPT; i++) {
        const int4 dv = dst4[i0 + i];
        const int4 sv = src4[i0 + i];
        if (dv.x == d) { ls[base] = sv.x; lc[base] = cosf(phase[sv.x * NN + d]); base++; }
        if (dv.y == d) { ls[base] = sv.y; lc[base] = cosf(phase[sv.y * NN + d]); base++; }
        if (dv.z == d) { ls[base] = sv.z; lc[base] = cosf(phase[sv.z * NN + d]); base++; }
        if (dv.w == d) { ls[base] = sv.w; lc[base] = cosf(phase[sv.w * NN + d]); base++; }
    }
    // pad to multiple of 4 with exact no-op edges
    const int n4 = (n + 3) & ~3;
    if (tid < n4 - n) { ls[n + tid] = 0; lc[n + tid] = 0.0f; }
    __syncthreads();

    const float rn = 1.0f / fmaxf((float)srccnt, 1.0f);

    // ---- Phase 2: unroll-4 gather-accumulate ----
    float4 acc0 = {0.f, 0.f, 0.f, 0.f};
    float4 acc1 = {0.f, 0.f, 0.f, 0.f};

    const int wdf = d * (FF / 4) + f4;                 // W4 offset for (d, f4)
    const int nb0 = (b0 + 0) * NN * (FF / 4) + f4;     // nf4 offset for batch b0
    const int nb1 = (b0 + 1) * NN * (FF / 4) + f4;

    for (int k = 0; k < n4; k += 4) {
        const int   s0 = ls[k + 0], s1 = ls[k + 1], s2 = ls[k + 2], s3 = ls[k + 3];
        const float c0 = lc[k + 0], c1 = lc[k + 1], c2 = lc[k + 2], c3 = lc[k + 3];

        float4 w0 = W4[s0 * (NN * FF / 4) + wdf];
        float4 w1 = W4[s1 * (NN * FF / 4) + wdf];
        float4 w2 = W4[s2 * (NN * FF / 4) + wdf];
        float4 w3 = W4[s3 * (NN * FF / 4) + wdf];

        const float4 x00 = nf4[nb0 + s0 * (FF / 4)];
        const float4 x01 = nf4[nb1 + s0 * (FF / 4)];
        const float4 x10 = nf4[nb0 + s1 * (FF / 4)];
        const float4 x11 = nf4[nb1 + s1 * (FF / 4)];
        const float4 x20 = nf4[nb0 + s2 * (FF / 4)];
        const float4 x21 = nf4[nb1 + s2 * (FF / 4)];
        const float4 x30 = nf4[nb0 + s3 * (FF / 4)];
        const float4 x31 = nf4[nb1 + s3 * (FF / 4)];

        w0.x *= c0; w0.y *= c0; w0.z *= c0; w0.w *= c0;
        w1.x *= c1; w1.y *= c1; w1.z *= c1; w1.w *= c1;
        w2.x *= c2; w2.y *= c2; w2.z *= c2; w2.w *= c2;
        w3.x *= c3; w3.y *= c3; w3.z *= c3; w3.w *= c3;

        fma4(acc0, x00, w0); fma4(acc1, x01, w0);
        fma4(acc0, x10, w1); fma4(acc1, x11, w1);
        fma4(acc0, x20, w2); fma4(acc1, x21, w2);
        fma4(acc0, x30, w3); fma4(acc1, x31, w3);
    }

    // ---- epilogue: normalize + store ----
    const int od = d * (FF / 4) + f4;
    float4 o;
    o.x = acc0.x * rn; o.y = acc0.y * rn; o.z = acc0.z * rn; o.w = acc0.w * rn;
    out4[(b0 + 0) * NN * (FF / 4) + od] = o;
    o.x = acc1.x * rn; o.y = acc1.y * rn; o.z = acc1.z * rn; o.w = acc1.w * rn;
    out4[(b0 + 1) * NN * (FF / 4) + od] = o;
}

// ---------------------------------------------------------------------------
// Launch: ONE kernel, no workspace needed.
// ---------------------------------------------------------------------------
extern "C" void kernel_launch(void* const* d_in, const int* in_sizes, int n_in,
                              void* d_out, int out_size, void* d_ws, size_t ws_size,
                              hipStream_t stream) {
    const float* nf    = (const float*)d_in[0];   // [B,N,F]
    const float* W     = (const float*)d_in[1];   // [N,N,F]
    const float* phase = (const float*)d_in[2];   // [N,N]
    const int*   src   = (const int*)d_in[3];     // [E]
    const int*   dst   = (const int*)d_in[4];     // [E]
    float*       out   = (float*)d_out;           // [B,N,F]

    dim3 grid(NN, FGROUPS);
    fused_propagate_kernel<<<grid, 256, 0, stream>>>(
        (const float4*)nf, (const float4*)W, phase, src, dst, (float4*)out);
}